// Round 1
// baseline (11997.314 us; speedup 1.0000x reference)
//
#include <hip/hip_runtime.h>
#include <math.h>

#define E 768
#define NH 12
#define HD 64
#define TT 1024
#define BB 2
#define LL 6
#define VV 50257
#define FF 3072
#define MROWS (BB * TT)   // 2048

// ---------------- embedding: x[b,t,:] = wte[tok] + wpe[t] ----------------
__global__ void embed_kernel(const int* __restrict__ tokens,
                             const float* __restrict__ wte,
                             const float* __restrict__ wpe,
                             float* __restrict__ x) {
    int row = blockIdx.x;            // b*TT + t
    int t = row & (TT - 1);
    int tok = tokens[row];
    const float* src = wte + (size_t)tok * E;
    const float* pos = wpe + (size_t)t * E;
    float* dst = x + (size_t)row * E;
    for (int i = threadIdx.x; i < E; i += blockDim.x)
        dst[i] = src[i] + pos[i];
}

// ---------------- layernorm (one block per row of E=768) ----------------
__global__ void ln_kernel(const float* __restrict__ in,
                          const float* __restrict__ scale,
                          const float* __restrict__ bias,
                          float* __restrict__ out) {
    int row = blockIdx.x;
    const float* xr = in + (size_t)row * E;
    float s = 0.f, s2 = 0.f;
    float v[3];
    int j = 0;
    for (int i = threadIdx.x; i < E; i += 256, j++) {
        float t = xr[i];
        v[j] = t; s += t; s2 += t * t;
    }
    __shared__ float rs[4], rs2[4];
    for (int off = 32; off; off >>= 1) {
        s += __shfl_xor(s, off);
        s2 += __shfl_xor(s2, off);
    }
    int wave = threadIdx.x >> 6;
    if ((threadIdx.x & 63) == 0) { rs[wave] = s; rs2[wave] = s2; }
    __syncthreads();
    if (threadIdx.x == 0) {
        float a = 0.f, b = 0.f;
        for (int w = 0; w < 4; w++) { a += rs[w]; b += rs2[w]; }
        rs[0] = a; rs2[0] = b;
    }
    __syncthreads();
    float mu = rs[0] * (1.0f / E);
    float var = rs2[0] * (1.0f / E) - mu * mu;
    float r = rsqrtf(var + 1e-5f);
    float* orow = out + (size_t)row * E;
    j = 0;
    for (int i = threadIdx.x; i < E; i += 256, j++)
        orow[i] = (v[j] - mu) * r * scale[i] + bias[i];
}

// ================= register-blocked SGEMM (NN layout) =================
// BM x 128 tile, 256 threads. TM = BM/16 rows x 8 cols per thread.
// A: M x K row-major (M multiple of BM), B: K x N row-major (N0+128 <= N),
// K multiple of 16. Optional bias (+N vec), GELU, residual (C += result).
template<int BM, int ACT, bool RESID, bool BIAS>
__device__ __forceinline__ void tile_body(const float* __restrict__ A,
        const float* __restrict__ B, const float* __restrict__ bias,
        float* __restrict__ C, int N, int K, int m0, int n0) {
    constexpr int TM = BM / 16;
    constexpr int NA = BM / 64;          // float4 A-loads per thread
    __shared__ alignas(16) float As[16][BM + 4];
    __shared__ alignas(16) float Bs[16][132];
    const int tid = threadIdx.x;
    const int tx = tid & 15, ty = tid >> 4;
    const int ar = tid >> 2, akq = (tid & 3) << 2;     // A staging: row, k-quad
    const int bk = tid >> 4, bnq = (tid & 15) << 2;    // B staging: k-row, n-quad
    const float* Ap = A + (size_t)(m0 + ar) * K + akq;
    const float* Bp = B + (size_t)bk * N + n0 + bnq;

    // register prefetch of K-slice 0
    float4 a_st[NA], b_st0, b_st1;
#pragma unroll
    for (int u = 0; u < NA; u++)
        a_st[u] = *(const float4*)(Ap + (size_t)(64 * u) * K);
    b_st0 = *(const float4*)(Bp);
    b_st1 = *(const float4*)(Bp + 64);

    float acc[TM][8] = {};
    for (int k0 = 0; k0 < K; k0 += 16) {
        // store staged regs -> LDS (A transposed to k-major)
#pragma unroll
        for (int u = 0; u < NA; u++) {
            As[akq + 0][64 * u + ar] = a_st[u].x;
            As[akq + 1][64 * u + ar] = a_st[u].y;
            As[akq + 2][64 * u + ar] = a_st[u].z;
            As[akq + 3][64 * u + ar] = a_st[u].w;
        }
        *(float4*)&Bs[bk][bnq]      = b_st0;
        *(float4*)&Bs[bk][64 + bnq] = b_st1;
        __syncthreads();
        // issue next K-slice loads early; HBM/L2 latency hides under compute
        if (k0 + 16 < K) {
#pragma unroll
            for (int u = 0; u < NA; u++)
                a_st[u] = *(const float4*)(Ap + (size_t)(64 * u) * K + k0 + 16);
            b_st0 = *(const float4*)(Bp + (size_t)(k0 + 16) * N);
            b_st1 = *(const float4*)(Bp + (size_t)(k0 + 16) * N + 64);
        }
#pragma unroll
        for (int kk = 0; kk < 16; kk++) {
            float a[TM], b[8];
            float4 t0 = *(const float4*)&As[kk][ty * 4];
            a[0] = t0.x; a[1] = t0.y; a[2] = t0.z; a[3] = t0.w;
            if constexpr (TM == 8) {
                float4 t1 = *(const float4*)&As[kk][64 + ty * 4];
                a[4] = t1.x; a[5] = t1.y; a[6] = t1.z; a[7] = t1.w;
            }
            float4 u0 = *(const float4*)&Bs[kk][tx * 4];
            float4 u1 = *(const float4*)&Bs[kk][64 + tx * 4];
            b[0] = u0.x; b[1] = u0.y; b[2] = u0.z; b[3] = u0.w;
            b[4] = u1.x; b[5] = u1.y; b[6] = u1.z; b[7] = u1.w;
#pragma unroll
            for (int i = 0; i < TM; i++)
#pragma unroll
                for (int j = 0; j < 8; j++)
                    acc[i][j] = fmaf(a[i], b[j], acc[i][j]);
        }
        __syncthreads();
    }
    // epilogue
#pragma unroll
    for (int i = 0; i < TM; i++) {
        int m = m0 + (i >> 2) * 64 + ty * 4 + (i & 3);
        float* Crow = C + (size_t)m * N + n0;
#pragma unroll
        for (int hf = 0; hf < 2; hf++) {
            int nb_ = hf * 64 + tx * 4;
            float4 v;
            v.x = acc[i][hf * 4 + 0]; v.y = acc[i][hf * 4 + 1];
            v.z = acc[i][hf * 4 + 2]; v.w = acc[i][hf * 4 + 3];
            if constexpr (BIAS) {
                const float* bp = bias + n0 + nb_;
                v.x += bp[0]; v.y += bp[1]; v.z += bp[2]; v.w += bp[3];
            }
            if constexpr (ACT == 1) {
                v.x = 0.5f * v.x * (1.0f + erff(v.x * 0.70710678118f));
                v.y = 0.5f * v.y * (1.0f + erff(v.y * 0.70710678118f));
                v.z = 0.5f * v.z * (1.0f + erff(v.z * 0.70710678118f));
                v.w = 0.5f * v.w * (1.0f + erff(v.w * 0.70710678118f));
            }
            if constexpr (RESID) {
                float4 r = *(const float4*)(Crow + nb_);
                v.x += r.x; v.y += r.y; v.z += r.z; v.w += r.w;
            }
            *(float4*)(Crow + nb_) = v;
        }
    }
}

template<int BM, int ACT, bool RESID, bool BIAS>
__global__ __launch_bounds__(256) void k_gemm(const float* __restrict__ A,
        const float* __restrict__ B, const float* __restrict__ bias,
        float* __restrict__ C, int N, int K) {
    tile_body<BM, ACT, RESID, BIAS>(A, B, bias, C, N, K,
                                    blockIdx.y * BM, blockIdx.x * 128);
}

// fused QKV: one launch covering all three E x E projections
__global__ __launch_bounds__(256) void k_qkv(const float* __restrict__ h,
        const float* __restrict__ Wq, const float* __restrict__ Wk,
        const float* __restrict__ Wv, float* __restrict__ qb,
        float* __restrict__ kb, float* __restrict__ vb) {
    int which = blockIdx.x / 6, nb = blockIdx.x % 6;   // E/128 = 6
    const float* W = which == 0 ? Wq : which == 1 ? Wk : Wv;
    float* Cp      = which == 0 ? qb : which == 1 ? kb : vb;
    tile_body<64, 0, false, false>(h, W, nullptr, Cp, E, E,
                                   blockIdx.y * 64, nb * 128);
}

// ---------------- logits: C = A(MxK) @ wte(VxK)^T, V-tail guarded ----------------
__global__ __launch_bounds__(256) void k_logits(const float* __restrict__ A,
        const float* __restrict__ Bt, float* __restrict__ C, int K) {
    __shared__ alignas(16) float As[16][132];
    __shared__ alignas(16) float Bs[16][132];
    const int tid = threadIdx.x;
    const int tx = tid & 15, ty = tid >> 4;
    const int m0 = blockIdx.y * 128, n0 = blockIdx.x * 128;
    const int ar = tid >> 2, akq = (tid & 3) << 2;
    const float* Ap = A + (size_t)(m0 + ar) * K + akq;
    const int nr0 = n0 + ar, nr1 = n0 + 64 + ar;
    const bool vv0 = nr0 < VV, vv1 = nr1 < VV;
    const float* Bp0 = Bt + (size_t)nr0 * K + akq;
    const float* Bp1 = Bt + (size_t)nr1 * K + akq;
    const float4 za = make_float4(0.f, 0.f, 0.f, 0.f);

    float4 a0s = *(const float4*)(Ap);
    float4 a1s = *(const float4*)(Ap + (size_t)64 * K);
    float4 b0s = vv0 ? *(const float4*)(Bp0) : za;
    float4 b1s = vv1 ? *(const float4*)(Bp1) : za;

    float acc[8][8] = {};
    for (int k0 = 0; k0 < K; k0 += 16) {
        As[akq + 0][ar] = a0s.x; As[akq + 1][ar] = a0s.y;
        As[akq + 2][ar] = a0s.z; As[akq + 3][ar] = a0s.w;
        As[akq + 0][64 + ar] = a1s.x; As[akq + 1][64 + ar] = a1s.y;
        As[akq + 2][64 + ar] = a1s.z; As[akq + 3][64 + ar] = a1s.w;
        Bs[akq + 0][ar] = b0s.x; Bs[akq + 1][ar] = b0s.y;
        Bs[akq + 2][ar] = b0s.z; Bs[akq + 3][ar] = b0s.w;
        Bs[akq + 0][64 + ar] = b1s.x; Bs[akq + 1][64 + ar] = b1s.y;
        Bs[akq + 2][64 + ar] = b1s.z; Bs[akq + 3][64 + ar] = b1s.w;
        __syncthreads();
        if (k0 + 16 < K) {
            a0s = *(const float4*)(Ap + k0 + 16);
            a1s = *(const float4*)(Ap + (size_t)64 * K + k0 + 16);
            b0s = vv0 ? *(const float4*)(Bp0 + k0 + 16) : za;
            b1s = vv1 ? *(const float4*)(Bp1 + k0 + 16) : za;
        }
#pragma unroll
        for (int kk = 0; kk < 16; kk++) {
            float a[8], b[8];
            float4 t0 = *(const float4*)&As[kk][ty * 4];
            float4 t1 = *(const float4*)&As[kk][64 + ty * 4];
            a[0] = t0.x; a[1] = t0.y; a[2] = t0.z; a[3] = t0.w;
            a[4] = t1.x; a[5] = t1.y; a[6] = t1.z; a[7] = t1.w;
            float4 u0 = *(const float4*)&Bs[kk][tx * 4];
            float4 u1 = *(const float4*)&Bs[kk][64 + tx * 4];
            b[0] = u0.x; b[1] = u0.y; b[2] = u0.z; b[3] = u0.w;
            b[4] = u1.x; b[5] = u1.y; b[6] = u1.z; b[7] = u1.w;
#pragma unroll
            for (int i = 0; i < 8; i++)
#pragma unroll
                for (int j = 0; j < 8; j++)
                    acc[i][j] = fmaf(a[i], b[j], acc[i][j]);
        }
        __syncthreads();
    }
#pragma unroll
    for (int i = 0; i < 8; i++) {
        int m = m0 + (i >> 2) * 64 + ty * 4 + (i & 3);
        float* Crow = C + (size_t)m * VV;
#pragma unroll
        for (int j = 0; j < 8; j++) {
            int n = n0 + (j >> 2) * 64 + tx * 4 + (j & 3);
            if (n < VV) Crow[n] = acc[i][j];
        }
    }
}

// ---------------- flash-style causal attention ----------------
__global__ void attn_kernel(const float* __restrict__ q,
                            const float* __restrict__ k,
                            const float* __restrict__ v,
                            float* __restrict__ o) {
    int idx = blockIdx.x;
    int tq = idx & (TT - 1);
    int h = (idx >> 10) % NH;
    int b = idx / (TT * NH);
    int lane = threadIdx.x;
    size_t rowq = ((size_t)(b * TT + tq)) * E + h * HD;
    float qd = q[rowq + lane] * 0.125f;  // 1/sqrt(64)
    float m = -INFINITY, l = 0.f, acc = 0.f;
    size_t base = ((size_t)b * TT) * E + h * HD;
    for (int tk = 0; tk <= tq; tk++) {
        size_t rk = base + (size_t)tk * E;
        float s = qd * k[rk + lane];
        for (int off = 32; off; off >>= 1) s += __shfl_xor(s, off);
        float mn = fmaxf(m, s);
        float corr = __expf(m - mn);
        float p = __expf(s - mn);
        l = l * corr + p;
        acc = acc * corr + p * v[rk + lane];
        m = mn;
    }
    o[rowq + lane] = acc / l;
}

extern "C" void kernel_launch(void* const* d_in, const int* in_sizes, int n_in,
                              void* d_out, int out_size, void* d_ws, size_t ws_size,
                              hipStream_t stream) {
    const int*   tokens = (const int*)d_in[0];
    const float* wte   = (const float*)d_in[1];
    const float* wpe   = (const float*)d_in[2];
    const float* Wq    = (const float*)d_in[3];
    const float* Wk    = (const float*)d_in[4];
    const float* Wv    = (const float*)d_in[5];
    const float* Wo    = (const float*)d_in[6];
    const float* bo    = (const float*)d_in[7];
    const float* ln1_s = (const float*)d_in[8];
    const float* ln1_b = (const float*)d_in[9];
    const float* W1    = (const float*)d_in[10];
    const float* b1    = (const float*)d_in[11];
    const float* W2    = (const float*)d_in[12];
    const float* b2    = (const float*)d_in[13];
    const float* ln2_s = (const float*)d_in[14];
    const float* ln2_b = (const float*)d_in[15];
    const float* lnf_s = (const float*)d_in[16];
    const float* lnf_b = (const float*)d_in[17];
    float* out = (float*)d_out;

    const size_t NE = (size_t)MROWS * E;   // 2048*768
    float* ws = (float*)d_ws;
    float* x  = ws;
    float* h  = x + NE;
    float* qb = h + NE;
    float* kb = qb + NE;
    float* vb = kb + NE;
    float* ob = vb + NE;
    float* mid = out;                      // 2048*3072 scratch at head of d_out

    embed_kernel<<<MROWS, 256, 0, stream>>>(tokens, wte, wpe, x);

    for (int l = 0; l < LL; l++) {
        const float* wq = Wq + (size_t)l * E * E;
        const float* wk = Wk + (size_t)l * E * E;
        const float* wv = Wv + (size_t)l * E * E;
        const float* wo = Wo + (size_t)l * E * E;
        const float* bo_l = bo + (size_t)l * E;
        const float* w1 = W1 + (size_t)l * E * FF;
        const float* b1_l = b1 + (size_t)l * FF;
        const float* w2 = W2 + (size_t)l * FF * E;
        const float* b2_l = b2 + (size_t)l * E;

        ln_kernel<<<MROWS, 256, 0, stream>>>(x, ln1_s + (size_t)l * E, ln1_b + (size_t)l * E, h);
        // fused QKV: 3 * (E/128) = 18 n-blocks, 32 m-blocks of 64 rows
        k_qkv<<<dim3(18, MROWS / 64), 256, 0, stream>>>(h, wq, wk, wv, qb, kb, vb);
        attn_kernel<<<BB * NH * TT, 64, 0, stream>>>(qb, kb, vb, ob);
        // Wo with fused bias + residual (in-place on x)
        k_gemm<64, 0, true, true><<<dim3(E / 128, MROWS / 64), 256, 0, stream>>>(
            ob, wo, bo_l, x, E, E);
        ln_kernel<<<MROWS, 256, 0, stream>>>(x, ln2_s + (size_t)l * E, ln2_b + (size_t)l * E, h);
        // W1 with fused bias + exact GELU
        k_gemm<64, 1, false, true><<<dim3(FF / 128, MROWS / 64), 256, 0, stream>>>(
            h, w1, b1_l, mid, FF, E);
        // W2 with fused bias + residual (in-place on x)
        k_gemm<64, 0, true, true><<<dim3(E / 128, MROWS / 64), 256, 0, stream>>>(
            mid, w2, b2_l, x, E, FF);
    }

    ln_kernel<<<MROWS, 256, 0, stream>>>(x, lnf_s, lnf_b, h);
    k_logits<<<dim3((VV + 127) / 128, MROWS / 128), 256, 0, stream>>>(h, wte, out, E);
}

// Round 2
// 8997.030 us; speedup vs baseline: 1.3335x; 1.3335x over previous
//
#include <hip/hip_runtime.h>
#include <math.h>

#define E 768
#define NH 12
#define HD 64
#define TT 1024
#define BB 2
#define LL 6
#define VV 50257
#define FF 3072
#define MROWS (BB * TT)   // 2048

typedef short bf16x8 __attribute__((ext_vector_type(8)));
typedef float f32x4  __attribute__((ext_vector_type(4)));

// split fp32 -> bf16 hi (truncate) + bf16 lo (truncate of remainder)
__device__ __forceinline__ void split2(float x, ushort& hi, ushort& lo) {
    unsigned u = __float_as_uint(x);
    unsigned hb = u & 0xffff0000u;
    float rem = x - __uint_as_float(hb);
    hi = (ushort)(u >> 16);
    lo = (ushort)(__float_as_uint(rem) >> 16);
}

// ---------------- embedding ----------------
__global__ void embed_kernel(const int* __restrict__ tokens,
                             const float* __restrict__ wte,
                             const float* __restrict__ wpe,
                             float* __restrict__ x) {
    int row = blockIdx.x;
    int t = row & (TT - 1);
    int tok = tokens[row];
    const float* src = wte + (size_t)tok * E;
    const float* pos = wpe + (size_t)t * E;
    float* dst = x + (size_t)row * E;
    for (int i = threadIdx.x; i < E; i += blockDim.x)
        dst[i] = src[i] + pos[i];
}

// ---------------- layernorm -> bf16 hi/lo pair ----------------
__global__ void ln_pair(const float* __restrict__ in,
                        const float* __restrict__ scale,
                        const float* __restrict__ bias,
                        ushort* __restrict__ ohi, ushort* __restrict__ olo) {
    int row = blockIdx.x;
    const float* xr = in + (size_t)row * E;
    float s = 0.f, s2 = 0.f;
    float v[3];
    int j = 0;
    for (int i = threadIdx.x; i < E; i += 256, j++) {
        float t = xr[i];
        v[j] = t; s += t; s2 += t * t;
    }
    __shared__ float rs[4], rs2[4];
    for (int off = 32; off; off >>= 1) {
        s += __shfl_xor(s, off);
        s2 += __shfl_xor(s2, off);
    }
    int wave = threadIdx.x >> 6;
    if ((threadIdx.x & 63) == 0) { rs[wave] = s; rs2[wave] = s2; }
    __syncthreads();
    if (threadIdx.x == 0) {
        float a = 0.f, b = 0.f;
        for (int w = 0; w < 4; w++) { a += rs[w]; b += rs2[w]; }
        rs[0] = a; rs2[0] = b;
    }
    __syncthreads();
    float mu = rs[0] * (1.0f / E);
    float var = rs2[0] * (1.0f / E) - mu * mu;
    float r = rsqrtf(var + 1e-5f);
    j = 0;
    for (int i = threadIdx.x; i < E; i += 256, j++) {
        float y = (v[j] - mu) * r * scale[i] + bias[i];
        ushort h, l; split2(y, h, l);
        ohi[(size_t)row * E + i] = h;
        olo[(size_t)row * E + i] = l;
    }
}

// ---------------- weight transpose + split: W[K][N] -> Wt_hi/lo[N][K] ----------------
__device__ __forceinline__ void txp_tile(const float* __restrict__ src,
        ushort* __restrict__ dhi, ushort* __restrict__ dlo,
        int K, int N, int kt, int nt) {
    __shared__ ushort Th[32][36], Tl[32][36];
    int tid = threadIdx.x;
    int k0 = kt * 32, n0 = nt * 32;
    int nl = tid & 31, k4 = tid >> 5;
#pragma unroll
    for (int r = 0; r < 4; r++) {
        int kl = k4 * 4 + r;
        float v = src[(size_t)(k0 + kl) * N + n0 + nl];
        ushort h, l; split2(v, h, l);
        Th[nl][kl] = h; Tl[nl][kl] = l;
    }
    __syncthreads();
    int nr = tid >> 3, kq = (tid & 7) * 4;
    ushort4 h4, l4_;
    h4.x = Th[nr][kq]; h4.y = Th[nr][kq + 1]; h4.z = Th[nr][kq + 2]; h4.w = Th[nr][kq + 3];
    l4_.x = Tl[nr][kq]; l4_.y = Tl[nr][kq + 1]; l4_.z = Tl[nr][kq + 2]; l4_.w = Tl[nr][kq + 3];
    *(ushort4*)&dhi[(size_t)(n0 + nr) * K + k0 + kq] = h4;
    *(ushort4*)&dlo[(size_t)(n0 + nr) * K + k0 + kq] = l4_;
}

#define EEu ((size_t)E * E)
#define EFu ((size_t)E * FF)
#define LSTRIDE (8 * EEu + 4 * EFu)

__global__ void txp_qkvo(const float* __restrict__ Wq, const float* __restrict__ Wk,
                         const float* __restrict__ Wv, const float* __restrict__ Wo,
                         ushort* __restrict__ wp) {
    int z = blockIdx.z, which = z & 3, l = z >> 2;
    const float* s = (which == 0 ? Wq : which == 1 ? Wk : which == 2 ? Wv : Wo)
                     + (size_t)l * EEu;
    ushort* dh = wp + (size_t)l * LSTRIDE + (size_t)which * 2 * EEu;
    txp_tile(s, dh, dh + EEu, E, E, blockIdx.y, blockIdx.x);
}
__global__ void txp_w1(const float* __restrict__ W1, ushort* __restrict__ wp) {
    int l = blockIdx.z;
    ushort* dh = wp + (size_t)l * LSTRIDE + 8 * EEu;
    txp_tile(W1 + (size_t)l * EFu, dh, dh + EFu, E, FF, blockIdx.y, blockIdx.x);
}
__global__ void txp_w2(const float* __restrict__ W2, ushort* __restrict__ wp) {
    int l = blockIdx.z;
    ushort* dh = wp + (size_t)l * LSTRIDE + 8 * EEu + 2 * EFu;
    txp_tile(W2 + (size_t)l * EFu, dh, dh + EFu, FF, E, blockIdx.y, blockIdx.x);
}

// ============ split-bf16 MFMA GEMM: C = A(MxK) * B(NxK)^T(pair) ============
// 128x128 tile, 256 thr = 4 waves (2x2 of 64x64). mfma_f32_16x16x32_bf16.
// A given as hi/lo bf16 [M][K]. B as hi/lo bf16 [N][K], or fp32 [N][K] if BCONV.
template<int BCONV, int ACT, int RESID, int BIAS, int OUTPAIR, int NGUARD>
__device__ __forceinline__ void mf_body(
        const ushort* __restrict__ Ahi, const ushort* __restrict__ Alo,
        const ushort* __restrict__ Bhi, const ushort* __restrict__ Blo,
        const float* __restrict__ Bf, const float* __restrict__ bias,
        float* __restrict__ C, ushort* __restrict__ Chi, ushort* __restrict__ Clo,
        int N, int K, int m0, int n0) {
    __shared__ ushort As[2][4][128][8];
    __shared__ ushort Bs[2][4][128][8];
    const int tid = threadIdx.x;
    const int lane = tid & 63, wid = tid >> 6;
    const int wr = (wid >> 1) * 64, wc = (wid & 1) * 64;
    const int fcol = lane & 15, fkg = lane >> 4;

    const int akg = tid & 3, am = tid >> 2;         // staging map
    const ushort* pAh0 = Ahi + (size_t)(m0 + am) * K + akg * 8;
    const ushort* pAh1 = pAh0 + (size_t)64 * K;
    const ushort* pAl0 = Alo + (size_t)(m0 + am) * K + akg * 8;
    const ushort* pAl1 = pAl0 + (size_t)64 * K;

    const ushort* pBh0 = nullptr; const ushort* pBh1 = nullptr;
    const ushort* pBl0 = nullptr; const ushort* pBl1 = nullptr;
    const float* pBf = nullptr;
    int bn = 0, bkh = 0; bool bval = true;
    if constexpr (BCONV) {
        bn = tid >> 1; bkh = (tid & 1) * 16;
        bval = (n0 + bn) < N;
        pBf = Bf + (size_t)(n0 + bn) * K + bkh;
    } else {
        pBh0 = Bhi + (size_t)(n0 + am) * K + akg * 8;
        pBh1 = pBh0 + (size_t)64 * K;
        pBl0 = Blo + (size_t)(n0 + am) * K + akg * 8;
        pBl1 = pBl0 + (size_t)64 * K;
    }

    bf16x8 rA0, rA1, rA2, rA3, rB0, rB1, rB2, rB3;
    float4 rF0, rF1, rF2, rF3;
    const float4 z4 = make_float4(0.f, 0.f, 0.f, 0.f);

    auto stage_load = [&](int k0) {
        rA0 = *(const bf16x8*)(pAh0 + k0);
        rA1 = *(const bf16x8*)(pAh1 + k0);
        rA2 = *(const bf16x8*)(pAl0 + k0);
        rA3 = *(const bf16x8*)(pAl1 + k0);
        if constexpr (BCONV) {
            rF0 = bval ? *(const float4*)(pBf + k0)      : z4;
            rF1 = bval ? *(const float4*)(pBf + k0 + 4)  : z4;
            rF2 = bval ? *(const float4*)(pBf + k0 + 8)  : z4;
            rF3 = bval ? *(const float4*)(pBf + k0 + 12) : z4;
        } else {
            rB0 = *(const bf16x8*)(pBh0 + k0);
            rB1 = *(const bf16x8*)(pBh1 + k0);
            rB2 = *(const bf16x8*)(pBl0 + k0);
            rB3 = *(const bf16x8*)(pBl1 + k0);
        }
    };

    stage_load(0);
    f32x4 acc[4][4] = {};

    for (int k0 = 0; k0 < K; k0 += 32) {
        *(bf16x8*)&As[0][akg][am][0]      = rA0;
        *(bf16x8*)&As[0][akg][am + 64][0] = rA1;
        *(bf16x8*)&As[1][akg][am][0]      = rA2;
        *(bf16x8*)&As[1][akg][am + 64][0] = rA3;
        if constexpr (BCONV) {
            const float4 f[4] = {rF0, rF1, rF2, rF3};
#pragma unroll
            for (int q = 0; q < 4; q++) {
                int kl = bkh + q * 4, kg = kl >> 3, ko = kl & 7;
                ushort4 h4, l4_;
                split2(f[q].x, h4.x, l4_.x); split2(f[q].y, h4.y, l4_.y);
                split2(f[q].z, h4.z, l4_.z); split2(f[q].w, h4.w, l4_.w);
                *(ushort4*)&Bs[0][kg][bn][ko] = h4;
                *(ushort4*)&Bs[1][kg][bn][ko] = l4_;
            }
        } else {
            *(bf16x8*)&Bs[0][akg][am][0]      = rB0;
            *(bf16x8*)&Bs[0][akg][am + 64][0] = rB1;
            *(bf16x8*)&Bs[1][akg][am][0]      = rB2;
            *(bf16x8*)&Bs[1][akg][am + 64][0] = rB3;
        }
        __syncthreads();
        if (k0 + 32 < K) stage_load(k0 + 32);

        bf16x8 ah[4], al[4], bh[4], bl[4];
#pragma unroll
        for (int f = 0; f < 4; f++) {
            ah[f] = *(const bf16x8*)&As[0][fkg][wr + f * 16 + fcol][0];
            al[f] = *(const bf16x8*)&As[1][fkg][wr + f * 16 + fcol][0];
            bh[f] = *(const bf16x8*)&Bs[0][fkg][wc + f * 16 + fcol][0];
            bl[f] = *(const bf16x8*)&Bs[1][fkg][wc + f * 16 + fcol][0];
        }
#pragma unroll
        for (int i = 0; i < 4; i++)
#pragma unroll
            for (int j = 0; j < 4; j++) {
                acc[i][j] = __builtin_amdgcn_mfma_f32_16x16x32_bf16(ah[i], bh[j], acc[i][j], 0, 0, 0);
                acc[i][j] = __builtin_amdgcn_mfma_f32_16x16x32_bf16(ah[i], bl[j], acc[i][j], 0, 0, 0);
                acc[i][j] = __builtin_amdgcn_mfma_f32_16x16x32_bf16(al[i], bh[j], acc[i][j], 0, 0, 0);
            }
        __syncthreads();
    }

#pragma unroll
    for (int i = 0; i < 4; i++)
#pragma unroll
        for (int j = 0; j < 4; j++) {
            int col = n0 + wc + j * 16 + fcol;
            if constexpr (NGUARD) { if (col >= N) continue; }
#pragma unroll
            for (int r = 0; r < 4; r++) {
                int row = m0 + wr + i * 16 + fkg * 4 + r;
                float v = acc[i][j][r];
                if constexpr (BIAS) v += bias[col];
                if constexpr (ACT) v = 0.5f * v * (1.0f + erff(v * 0.70710678118f));
                size_t off = (size_t)row * N + col;
                if constexpr (RESID) v += C[off];
                if constexpr (OUTPAIR) {
                    ushort h, l; split2(v, h, l);
                    Chi[off] = h; Clo[off] = l;
                } else {
                    C[off] = v;
                }
            }
        }
}

template<int BCONV, int ACT, int RESID, int BIAS, int OUTPAIR, int NGUARD>
__global__ __launch_bounds__(256) void k_mf(
        const ushort* __restrict__ Ahi, const ushort* __restrict__ Alo,
        const ushort* __restrict__ Bhi, const ushort* __restrict__ Blo,
        const float* __restrict__ Bf, const float* __restrict__ bias,
        float* __restrict__ C, ushort* __restrict__ Chi, ushort* __restrict__ Clo,
        int N, int K) {
    mf_body<BCONV, ACT, RESID, BIAS, OUTPAIR, NGUARD>(
        Ahi, Alo, Bhi, Blo, Bf, bias, C, Chi, Clo, N, K,
        blockIdx.y * 128, blockIdx.x * 128);
}

// fused QKV (3 x ExE projections, one launch)
__global__ __launch_bounds__(256) void k_qkv_mf(
        const ushort* __restrict__ Ahi, const ushort* __restrict__ Alo,
        const ushort* __restrict__ lb,   // layer weight-pair base
        float* __restrict__ qb, float* __restrict__ kb, float* __restrict__ vb) {
    int which = blockIdx.x / 6, nb = blockIdx.x % 6;
    const ushort* Bh = lb + (size_t)which * 2 * EEu;
    const ushort* Bl = Bh + EEu;
    float* C = which == 0 ? qb : which == 1 ? kb : vb;
    mf_body<0, 0, 0, 0, 0, 0>(Ahi, Alo, Bh, Bl, nullptr, nullptr,
                              C, nullptr, nullptr, E, E,
                              blockIdx.y * 128, nb * 128);
}

// ---------------- flash-style causal attention (pair output) ----------------
__global__ void attn_kernel(const float* __restrict__ q,
                            const float* __restrict__ k,
                            const float* __restrict__ v,
                            ushort* __restrict__ ohi, ushort* __restrict__ olo) {
    int idx = blockIdx.x;
    int tq = idx & (TT - 1);
    int h = (idx >> 10) % NH;
    int b = idx / (TT * NH);
    int lane = threadIdx.x;
    size_t rowq = ((size_t)(b * TT + tq)) * E + h * HD;
    float qd = q[rowq + lane] * 0.125f;
    float m = -INFINITY, l = 0.f, acc = 0.f;
    size_t base = ((size_t)b * TT) * E + h * HD;
    for (int tk = 0; tk <= tq; tk++) {
        size_t rk = base + (size_t)tk * E;
        float s = qd * k[rk + lane];
        for (int off = 32; off; off >>= 1) s += __shfl_xor(s, off);
        float mn = fmaxf(m, s);
        float corr = __expf(m - mn);
        float p = __expf(s - mn);
        l = l * corr + p;
        acc = acc * corr + p * v[rk + lane];
        m = mn;
    }
    float r = acc / l;
    ushort hh, ll; split2(r, hh, ll);
    ohi[rowq + lane] = hh;
    olo[rowq + lane] = ll;
}

extern "C" void kernel_launch(void* const* d_in, const int* in_sizes, int n_in,
                              void* d_out, int out_size, void* d_ws, size_t ws_size,
                              hipStream_t stream) {
    const int*   tokens = (const int*)d_in[0];
    const float* wte   = (const float*)d_in[1];
    const float* wpe   = (const float*)d_in[2];
    const float* Wq    = (const float*)d_in[3];
    const float* Wk    = (const float*)d_in[4];
    const float* Wv    = (const float*)d_in[5];
    const float* Wo    = (const float*)d_in[6];
    const float* bo    = (const float*)d_in[7];
    const float* ln1_s = (const float*)d_in[8];
    const float* ln1_b = (const float*)d_in[9];
    const float* W1    = (const float*)d_in[10];
    const float* b1    = (const float*)d_in[11];
    const float* W2    = (const float*)d_in[12];
    const float* b2    = (const float*)d_in[13];
    const float* ln2_s = (const float*)d_in[14];
    const float* ln2_b = (const float*)d_in[15];
    const float* lnf_s = (const float*)d_in[16];
    const float* lnf_b = (const float*)d_in[17];
    float* out = (float*)d_out;

    const size_t NE = (size_t)MROWS * E;
    float* ws = (float*)d_ws;
    float*  x    = ws;                               // NE f32
    ushort* hhi  = (ushort*)(x + NE);                // NE
    ushort* hlo  = hhi + NE;                         // NE
    float*  qb   = (float*)(hlo + NE);               // NE f32
    float*  kb   = qb + NE;
    float*  vb   = kb + NE;
    ushort* obhi = (ushort*)(vb + NE);               // NE
    ushort* oblo = obhi + NE;                        // NE
    // mid pair aliases the q/k/v/ob region (disjoint lifetimes)
    ushort* midhi = (ushort*)qb;                     // MROWS*FF
    ushort* midlo = midhi + (size_t)MROWS * FF;

    ushort* wp = (ushort*)d_out;   // weight-pair scratch; overwritten by logits at end

    // ---- weight transpose+split (per launch) ----
    txp_qkvo<<<dim3(24, 24, 24), 256, 0, stream>>>(Wq, Wk, Wv, Wo, wp);
    txp_w1  <<<dim3(96, 24, 6), 256, 0, stream>>>(W1, wp);
    txp_w2  <<<dim3(24, 96, 6), 256, 0, stream>>>(W2, wp);

    embed_kernel<<<MROWS, 256, 0, stream>>>(tokens, wte, wpe, x);

    for (int l = 0; l < LL; l++) {
        ushort* lb_w = wp + (size_t)l * LSTRIDE;
        const ushort* woh = lb_w + 6 * EEu;
        const ushort* wol = lb_w + 7 * EEu;
        const ushort* w1h = lb_w + 8 * EEu;
        const ushort* w1l = w1h + EFu;
        const ushort* w2h = w1h + 2 * EFu;
        const ushort* w2l = w1h + 3 * EFu;
        const float* bo_l = bo + (size_t)l * E;
        const float* b1_l = b1 + (size_t)l * FF;
        const float* b2_l = b2 + (size_t)l * E;

        ln_pair<<<MROWS, 256, 0, stream>>>(x, ln1_s + (size_t)l * E, ln1_b + (size_t)l * E, hhi, hlo);
        k_qkv_mf<<<dim3(18, MROWS / 128), 256, 0, stream>>>(hhi, hlo, lb_w, qb, kb, vb);
        attn_kernel<<<BB * NH * TT, 64, 0, stream>>>(qb, kb, vb, obhi, oblo);
        k_mf<0, 0, 1, 1, 0, 0><<<dim3(6, MROWS / 128), 256, 0, stream>>>(
            obhi, oblo, woh, wol, nullptr, bo_l, x, nullptr, nullptr, E, E);
        ln_pair<<<MROWS, 256, 0, stream>>>(x, ln2_s + (size_t)l * E, ln2_b + (size_t)l * E, hhi, hlo);
        k_mf<0, 1, 0, 1, 1, 0><<<dim3(24, MROWS / 128), 256, 0, stream>>>(
            hhi, hlo, w1h, w1l, nullptr, b1_l, nullptr, midhi, midlo, FF, E);
        k_mf<0, 0, 1, 1, 0, 0><<<dim3(6, MROWS / 128), 256, 0, stream>>>(
            midhi, midlo, w2h, w2l, nullptr, b2_l, x, nullptr, nullptr, E, FF);
    }

    ln_pair<<<MROWS, 256, 0, stream>>>(x, lnf_s, lnf_b, hhi, hlo);
    k_mf<1, 0, 0, 0, 0, 1><<<dim3((VV + 127) / 128, MROWS / 128), 256, 0, stream>>>(
        hhi, hlo, nullptr, nullptr, wte, nullptr, out, nullptr, nullptr, VV, E);
}